// Round 13
// baseline (209.058 us; speedup 1.0000x reference)
//
#include <hip/hip_runtime.h>
#include <hip/hip_bf16.h>
#include <stdint.h>

#define B_ 2
#define N_ 2048
#define M_ 2048
#define C_ 1024
#define H_ 16
#define D_ 64

typedef __attribute__((ext_vector_type(8))) short s16x8;
typedef __attribute__((ext_vector_type(4))) short s16x4;
typedef __attribute__((ext_vector_type(4))) float f32x4;
typedef __attribute__((ext_vector_type(16))) float f32x16;

__device__ __attribute__((always_inline)) inline short f2b(float f){
    __hip_bfloat16 h = __float2bfloat16(f); short s; __builtin_memcpy(&s, &h, 2); return s;
}
__device__ __attribute__((always_inline)) inline float b2f(short s){
    __hip_bfloat16 h; __builtin_memcpy(&h, &s, 2); return __bfloat162float(h);
}

#define MFMA16(a,b,c) __builtin_amdgcn_mfma_f32_16x16x32_bf16(a,b,c,0,0,0)
#define MFMA32(a,b,c) __builtin_amdgcn_mfma_f32_32x32x16_bf16(a,b,c,0,0,0)

__device__ __attribute__((always_inline)) inline void gl_lds16(const void* g, void* l){
    __builtin_amdgcn_global_load_lds((__attribute__((address_space(1))) void*)g,
                                     (__attribute__((address_space(3))) void*)l, 16, 0, 0);
}
// pack two f32 -> one u32 of 2 bf16 (RNE), low short = first arg
__device__ __attribute__((always_inline)) inline unsigned cvtpk(float lo, float hi){
    unsigned r;
    asm("v_cvt_pk_bf16_f32 %0, %1, %2" : "=v"(r) : "v"(lo), "v"(hi));
    return r;
}
// a -> [a_lo | b_lo], b -> [a_hi | b_hi] across the lane<32 / lane>=32 split
__device__ __attribute__((always_inline)) inline void lane32swap(unsigned &a, unsigned &b){
    asm("v_permlane32_swap_b32 %0, %1" : "+v"(a), "+v"(b));
}

// ---------------- fused f32 -> bf16 convert: [query|key|Wq|Wk|Wv|Wo] -> ws[0..12M) ----
__global__ void cvt_all(const float* __restrict__ q, const float* __restrict__ k,
                        const float* __restrict__ wq, const float* __restrict__ wk,
                        const float* __restrict__ wv, const float* __restrict__ wo,
                        short* __restrict__ dst){
    long i = ((long)blockIdx.x * 256 + threadIdx.x) * 8;
    const float* src; long off;
    if      (i <  4194304L){ src = q;  off = i; }
    else if (i <  8388608L){ src = k;  off = i - 4194304L; }
    else if (i <  9437184L){ src = wq; off = i - 8388608L; }
    else if (i < 10485760L){ src = wk; off = i - 9437184L; }
    else if (i < 11534336L){ src = wv; off = i - 10485760L; }
    else                   { src = wo; off = i - 11534336L; }
    float4 a = *(const float4*)(src + off);
    float4 b = *(const float4*)(src + off + 4);
    s16x8 o;
    o[0]=f2b(a.x); o[1]=f2b(a.y); o[2]=f2b(a.z); o[3]=f2b(a.w);
    o[4]=f2b(b.x); o[5]=f2b(b.y); o[6]=f2b(b.z); o[7]=f2b(b.w);
    *(s16x8*)(dst + i) = o;
}

// ---------------- fused QKV projection GEMM ----------------
// A = qbf (n0<1024) or kbf; W = [Wq;Wk;Wv] (3072,1024) bf16 row-major.
// Epilogue: q -> +bq plain store; k -> fused RoPE (f32, in-register pair j/j+2) store;
// v -> +bv, LDS-transposed coalesced store to vT[b,h,d,m].
__global__ __launch_bounds__(256, 3) void gemm_qkv(
    const short* __restrict__ qbf, const short* __restrict__ kbf,
    const short* __restrict__ W,
    const float* __restrict__ bq, const float* __restrict__ bv,
    const int* __restrict__ kpos,
    short* __restrict__ qproj, short* __restrict__ kproj, short* __restrict__ vT)
{
    // sb: As = [0,4096), Bs = [4096,8192) during the k-loop;
    // whole 8704 shorts reused as Vt[64][136] in the V transpose epilogue.
    __shared__ short sb[8704];
    short* As = sb;
    short* Bs = sb + 4096;
    const int n0 = blockIdx.x * 128, m0 = blockIdx.y * 128;
    const int sel = n0 >> 10;                 // 0=q, 1=k, 2=v (block-uniform)
    const short* A = (sel == 0) ? qbf : kbf;
    const int tid = threadIdx.x, lane = tid & 63, wave = tid >> 6;
    const int quad = lane >> 4, l16 = lane & 15;
    const int wr = (wave >> 1) * 64, wc = (wave & 1) * 64;
    const int srow = lane >> 2, scol = (lane & 3) * 8;

    f32x4 acc[4][4] = {};

    const short* Ag = A + (size_t)(m0 + wave * 32 + srow) * C_ + scol;
    const short* Bg = W + (size_t)(n0 + wave * 32 + srow) * C_ + scol;
    short* lA0 = As + (wave * 32) * 32;
    short* lA1 = As + (wave * 32 + 16) * 32;
    short* lB0 = Bs + (wave * 32) * 32;
    short* lB1 = Bs + (wave * 32 + 16) * 32;

    for (int k0 = 0; k0 < C_; k0 += 32){
        __syncthreads();
        gl_lds16(Ag + k0, lA0);
        gl_lds16(Ag + k0 + 16 * (size_t)C_, lA1);
        gl_lds16(Bg + k0, lB0);
        gl_lds16(Bg + k0 + 16 * (size_t)C_, lB1);
        __syncthreads();
        s16x8 af[4], bfr[4];
        #pragma unroll
        for (int t = 0; t < 4; t++) af[t]  = *(const s16x8*)&As[(wr + t*16 + l16) * 32 + quad * 8];
        #pragma unroll
        for (int t = 0; t < 4; t++) bfr[t] = *(const s16x8*)&Bs[(wc + t*16 + l16) * 32 + quad * 8];
        #pragma unroll
        for (int i = 0; i < 4; i++)
            #pragma unroll
            for (int j = 0; j < 4; j++)
                acc[i][j] = MFMA16(af[i], bfr[j], acc[i][j]);
    }

    // C/D layout (m89-verified): row(m) = quad*4 + r, col(n) = l16
    if (sel == 0){
        #pragma unroll
        for (int j = 0; j < 4; j++){
            int c = n0 + wc + j * 16 + l16;
            float bb = bq[c];
            #pragma unroll
            for (int i = 0; i < 4; i++){
                int row = m0 + wr + i * 16 + quad * 4;
                #pragma unroll
                for (int r = 0; r < 4; r++)
                    qproj[(size_t)(row + r) * C_ + c] = f2b(acc[i][j][r] + bb);
            }
        }
    } else if (sel == 1){
        // K path: fused RoPE in f32. Pair (d, d+32) = (acc[i][j2], acc[i][j2+2]),
        // d = (wc + j2*16 + l16) & 63 in [0,32). row indexes kpos directly ([B*M]).
        #pragma unroll
        for (int j2 = 0; j2 < 2; j2++){
            int c1 = n0 - 1024 + wc + j2 * 16 + l16;     // col in [0,1024), d = c1&63 < 32
            int irot = c1 & 63;
            float invf = exp2f((float)irot * (-13.287712379549449f / 32.0f));
            #pragma unroll
            for (int i = 0; i < 4; i++){
                int row = m0 + wr + i * 16 + quad * 4;
                #pragma unroll
                for (int r = 0; r < 4; r++){
                    float pos = (float)kpos[row + r];
                    float ang = pos * invf;
                    float cs = __cosf(ang), sn = __sinf(ang);
                    float x1 = acc[i][j2][r], x2 = acc[i][j2 + 2][r];
                    kproj[(size_t)(row + r) * C_ + c1]      = f2b(x1 * cs - x2 * sn);
                    kproj[(size_t)(row + r) * C_ + c1 + 32] = f2b(x2 * cs + x1 * sn);
                }
            }
        }
    } else {
        // V: +bv, LDS transpose then coalesced store.
        short* Vt = sb;                       // [64 cols][136 stride] shorts
        const int bat = m0 >> 11;
        const int mbase = m0 & 2047;
        #pragma unroll
        for (int p = 0; p < 2; p++){
            __syncthreads();
            if ((wave & 1) == p){
                #pragma unroll
                for (int j = 0; j < 4; j++){
                    int c_local = j * 16 + l16;              // 0..63
                    float bb = bv[n0 - 2048 + p * 64 + c_local];
                    #pragma unroll
                    for (int i = 0; i < 4; i++){
                        int row = wr + i * 16 + quad * 4;    // 0..127
                        unsigned u0 = (unsigned)(unsigned short)f2b(acc[i][j][0] + bb) |
                                      ((unsigned)(unsigned short)f2b(acc[i][j][1] + bb) << 16);
                        unsigned u1 = (unsigned)(unsigned short)f2b(acc[i][j][2] + bb) |
                                      ((unsigned)(unsigned short)f2b(acc[i][j][3] + bb) << 16);
                        uint2 u; u.x = u0; u.y = u1;
                        *(uint2*)&Vt[c_local * 136 + row] = u;
                    }
                }
            }
            __syncthreads();
            #pragma unroll
            for (int it = 0; it < 4; it++){
                int qq = it * 256 + tid;
                int c_local = qq >> 4, mm = (qq & 15) * 8;
                int colg = n0 - 2048 + p * 64 + c_local;
                int hh = colg >> 6, dd = colg & 63;
                s16x8 v = *(const s16x8*)&Vt[c_local * 136 + mm];
                *(s16x8*)&vT[(((size_t)(bat * H_ + hh)) * D_ + dd) * M_ + mbase + mm] = v;
            }
        }
    }
}

// ---------------- final projection + bias + residual (f32 out) ----------------
__global__ __launch_bounds__(256, 4) void gemm_out(
    const short* __restrict__ A, const short* __restrict__ W,
    const float* __restrict__ bias, const float* __restrict__ resid,
    float* __restrict__ outf)
{
    __shared__ short As[128 * 32];
    __shared__ short Bs[64 * 32];
    const int n0 = blockIdx.x * 64, m0 = blockIdx.y * 128;
    const int tid = threadIdx.x, lane = tid & 63, wave = tid >> 6;
    const int quad = lane >> 4, l16 = lane & 15;
    const int srow = lane >> 2, scol = (lane & 3) * 8;

    f32x4 acc[2][4] = {};
    const short* Ag = A + (size_t)(m0 + wave * 32 + srow) * C_ + scol;
    const short* Bg = W + (size_t)(n0 + wave * 16 + srow) * C_ + scol;
    short* lA0 = As + (wave * 32) * 32;
    short* lA1 = As + (wave * 32 + 16) * 32;
    short* lB  = Bs + (wave * 16) * 32;

    for (int k0 = 0; k0 < C_; k0 += 32){
        __syncthreads();
        gl_lds16(Ag + k0, lA0);
        gl_lds16(Ag + k0 + 16 * (size_t)C_, lA1);
        gl_lds16(Bg + k0, lB);
        __syncthreads();
        s16x8 af[2], bfr[4];
        #pragma unroll
        for (int t = 0; t < 2; t++) af[t]  = *(const s16x8*)&As[(wave*32 + t*16 + l16) * 32 + quad * 8];
        #pragma unroll
        for (int t = 0; t < 4; t++) bfr[t] = *(const s16x8*)&Bs[(t*16 + l16) * 32 + quad * 8];
        #pragma unroll
        for (int i = 0; i < 2; i++)
            #pragma unroll
            for (int j = 0; j < 4; j++)
                acc[i][j] = MFMA16(af[i], bfr[j], acc[i][j]);
    }

    #pragma unroll
    for (int j = 0; j < 4; j++){
        int c = n0 + j * 16 + l16;
        float bb = bias[c];
        #pragma unroll
        for (int i = 0; i < 2; i++){
            int row = m0 + wave * 32 + i * 16 + quad * 4;
            #pragma unroll
            for (int r = 0; r < 4; r++){
                size_t idx = (size_t)(row + r) * C_ + c;
                outf[idx] = acc[i][j][r] + bb + resid[idx];
            }
        }
    }
}

// ---- flash_attn helper macros (straight-line; all indices compile-time-friendly) ----
// full compute of one KV tile living in buf BI: ds_read K/V frags, QK^T, softmax exp,
// in-register P repack (cvt_pk + permlane32_swap), PV accumulate.
#define COMPUTE_TILE(BI) do {                                                         \
    const short* Kp_ = &smem[(BI) * 4352];                                            \
    const short* Vp_ = &smem[17408 + (BI) * 4352];                                    \
    s16x4 kf_[4][2];                                                                  \
    _Pragma("unroll")                                                                 \
    for (int c = 0; c < 4; c++){                                                      \
        const short* a_ = &Kp_[(kq * 32 + l32) * 68 + c * 16 + hi * 8];               \
        kf_[c][0] = *(const s16x4*)a_; kf_[c][1] = *(const s16x4*)(a_ + 4);           \
    }                                                                                 \
    s16x8 vf_[2][2];                                                                  \
    _Pragma("unroll")                                                                 \
    for (int dt = 0; dt < 2; dt++)                                                    \
        _Pragma("unroll")                                                             \
        for (int c = 0; c < 2; c++){                                                  \
            const short* a_ = &Vp_[(dt * 32 + l32) * 68 + kq * 32 + c * 16 + hi * 8]; \
            vf_[dt][c] = __builtin_shufflevector(*(const s16x4*)a_,                   \
                                                 *(const s16x4*)(a_ + 4),             \
                                                 0,1,2,3,4,5,6,7);                    \
        }                                                                             \
    s16x8 pf_[2][2];                                                                  \
    _Pragma("unroll")                                                                 \
    for (int qt = 0; qt < 2; qt++){                                                   \
        f32x16 sv_ = {};                                                              \
        _Pragma("unroll")                                                             \
        for (int c = 0; c < 4; c++){                                                  \
            s16x8 ka_ = __builtin_shufflevector(kf_[c][0], kf_[c][1],                 \
                                                0,1,2,3,4,5,6,7);                     \
            sv_ = MFMA32(ka_, qf[qt][c], sv_);                                        \
        }                                                                             \
        float pe_[16];                                                                \
        _Pragma("unroll")                                                             \
        for (int e = 0; e < 16; e++) pe_[e] = __builtin_amdgcn_exp2f(sv_[e]);         \
        float ls_ = 0.f;                                                              \
        _Pragma("unroll")                                                             \
        for (int e = 0; e < 16; e += 4) ls_ += (pe_[e]+pe_[e+1]) + (pe_[e+2]+pe_[e+3]);\
        lacc[qt] += ls_;                                                              \
        _Pragma("unroll")                                                             \
        for (int c = 0; c < 2; c++){                                                  \
            unsigned a1_ = cvtpk(pe_[8*c + 0], pe_[8*c + 1]);                         \
            unsigned a2_ = cvtpk(pe_[8*c + 2], pe_[8*c + 3]);                         \
            unsigned b1_ = cvtpk(pe_[8*c + 4], pe_[8*c + 5]);                         \
            unsigned b2_ = cvtpk(pe_[8*c + 6], pe_[8*c + 7]);                         \
            lane32swap(a1_, b1_);                                                     \
            lane32swap(a2_, b2_);                                                     \
            union { unsigned u[4]; s16x8 v; } pk_;                                    \
            pk_.u[0] = a1_; pk_.u[1] = a2_; pk_.u[2] = b1_; pk_.u[3] = b2_;           \
            pf_[qt][c] = pk_.v;                                                       \
        }                                                                             \
    }                                                                                 \
    _Pragma("unroll")                                                                 \
    for (int qt = 0; qt < 2; qt++)                                                    \
        _Pragma("unroll")                                                             \
        for (int dt = 0; dt < 2; dt++)                                                \
            _Pragma("unroll")                                                         \
            for (int c = 0; c < 2; c++)                                               \
                oacc[qt][dt] = MFMA32(pf_[qt][c], vf_[dt][c], oacc[qt][dt]);          \
} while(0)

// ds_write one staged tile (regs KR/VR) into buf BUF
#define WRITE_SET(BUF, KR, VR) do {                                                   \
    _Pragma("unroll")                                                                 \
    for (int ii = 0; ii < 2; ii++){                                                   \
        int row_ = srow0 + 32 * ii;                                                   \
        short* kd_ = &smem[(BUF) * 4352 + row_ * 68 + sseg];                          \
        *(uint2*)kd_ = KR[ii].u[0]; *(uint2*)(kd_ + 4) = KR[ii].u[1];                 \
        short* vd_ = &smem[17408 + (BUF) * 4352 + row_ * 68 + sseg];                  \
        *(uint2*)vd_ = VR[ii].u[0]; *(uint2*)(vd_ + 4) = VR[ii].u[1];                 \
    }                                                                                 \
} while(0)

// issue global loads of KV tile T into regs KR/VR
#define LOAD_SET(KR, VR, T) do {                                                      \
    _Pragma("unroll")                                                                 \
    for (int ii = 0; ii < 2; ii++){                                                   \
        int row_ = srow0 + 32 * ii;                                                   \
        KR[ii].v = *(const s16x8*)&kg[((size_t)((T) * 64 + row_)) * C_ + sseg];       \
        VR[ii].v = *(const s16x8*)&vg[(size_t)row_ * M_ + (T) * 64 + sseg];           \
    }                                                                                 \
} while(0)

// ---------------- Flash attention (128-q, depth-2 pipe, 2 tiles per barrier) --------
// Round-13: halve barrier count (33 -> 17). Interval i computes tiles 2i,2i+1 from
// bufs {p,p+1} (p = (i&1)*2), ds_writes tiles 2i+2/2i+3 into bufs {p^2,p^2+1} (free
// since previous barrier; skew <= 1 interval => reader/writer buffer sets disjoint),
// issues loads for 2i+4/2i+5 (two staging reg sets), then ONE lgkmcnt(0)+s_barrier.
// vmcnt stays counted (never drained at barriers). XCD-chunked grid swizzle (r12:
// FETCH 69.7->12.4 MB). P in-register via cvt_pk + permlane32_swap.
__global__ __launch_bounds__(256, 2) void flash_attn(
    const short* __restrict__ q, const short* __restrict__ k,
    const short* __restrict__ vt, short* __restrict__ o,
    const int* __restrict__ qpos)
{
    // shorts: K[4] @0 (4*64*68=17408), V[4] @17408, Lsum/Linv @34816 (256 f32)
    __shared__ short smem[35328];
    // XCD-chunked bijective swizzle (512 % 8 == 0): xcd = bid&7 gets 64 contiguous ids
    const int bid = blockIdx.x;
    const int wgid = (bid & 7) * 64 + (bid >> 3);
    const int y = wgid >> 4;                 // (b,h) group: 4 per XCD
    const int n0 = (wgid & 15) * 128;        // q-block
    const int b = y >> 4, h = y & 15;
    const int tid = threadIdx.x, lane = tid & 63, wave = tid >> 6;
    const int hi = lane >> 5, l32 = lane & 31;
    const int wq = wave & 1, kq = wave >> 1;

    // Q fragments (B-operand: lane n = q row, k = d), with fused RoPE + scale*log2e
    s16x8 qf[2][4];
    const float fac = 0.18033688011112042f;   // 0.125 * log2(e)
    #pragma unroll
    for (int qt = 0; qt < 2; qt++){
        int qrow = n0 + wq * 64 + qt * 32 + l32;
        const short* qg = &q[((size_t)(b * N_ + qrow)) * C_ + h * D_];
        float pos = (float)qpos[b * N_ + qrow];
        s16x8 raw[4];
        #pragma unroll
        for (int c = 0; c < 4; c++) raw[c] = *(const s16x8*)&qg[c * 16 + hi * 8];
        #pragma unroll
        for (int c = 0; c < 2; c++){
            s16x8 olo, ohi8;
            #pragma unroll
            for (int j = 0; j < 8; j++){
                int irot = c * 16 + hi * 8 + j;
                float invf = exp2f((float)irot * (-13.287712379549449f / 32.0f));
                float ang = pos * invf;
                float cs = __cosf(ang), sn = __sinf(ang);
                float x1 = b2f(raw[c][j]), x2 = b2f(raw[c + 2][j]);
                olo[j]  = f2b((x1 * cs - x2 * sn) * fac);
                ohi8[j] = f2b((x2 * cs + x1 * sn) * fac);
            }
            qf[qt][c] = olo; qf[qt][c + 2] = ohi8;
        }
    }

    const short* kg = k  + (size_t)(b * M_) * C_ + h * D_;
    const short* vg = vt + ((size_t)(b * H_ + h)) * D_ * M_;
    const int srow0 = tid >> 3, sseg = (tid & 7) * 8;

    union V8 { s16x8 v; uint2 u[2]; };
    V8 kregA[2], vregA[2], kregB[2], vregB[2];

    // prologue: tiles 0,1 -> regs -> bufs 0,1; tiles 2,3 -> regs (held); barrier
    LOAD_SET(kregA, vregA, 0);
    LOAD_SET(kregB, vregB, 1);
    WRITE_SET(0, kregA, vregA);
    WRITE_SET(1, kregB, vregB);
    LOAD_SET(kregA, vregA, 2);
    LOAD_SET(kregB, vregB, 3);
    asm volatile("s_waitcnt lgkmcnt(0)" ::: "memory");
    __builtin_amdgcn_s_barrier();

    f32x16 zero16 = {};
    f32x16 oacc[2][2] = {zero16, zero16, zero16, zero16};
    float lacc[2] = {0.f, 0.f};

    for (int iv = 0; iv < 16; iv++){
        const int p = (iv & 1) << 1;           // current bufs {p, p+1}; write {p^2, p^2+1}
        // tile 2*iv from buf p
        COMPUTE_TILE(p);
        // ds_write tile 2*iv+2 (regs loaded interval iv-1; vmcnt wait lands here
        // with a full interval of slack)
        if (iv < 15) WRITE_SET(p ^ 2, kregA, vregA);
        // tile 2*iv+1 from buf p+1
        COMPUTE_TILE(p + 1);
        if (iv < 15) WRITE_SET((p ^ 2) + 1, kregB, vregB);
        // issue loads for tiles 2*iv+4 / 2*iv+5 (stay in flight across next interval)
        if (iv < 14){
            LOAD_SET(kregA, vregA, 2 * iv + 4);
            LOAD_SET(kregB, vregB, 2 * iv + 5);
        }
        // drain LDS ops (my ds_writes visible), raw barrier (vmcnt NOT drained)
        asm volatile("s_waitcnt lgkmcnt(0)" ::: "memory");
        __builtin_amdgcn_s_barrier();
    }

    __syncthreads();   // full drain before overlaying K/V buffers

    float* LO   = (float*)smem;            // [128][65] f32 (overlays K bufs, 33.3KB)
    float* Lsum = (float*)&smem[34816];    // 128 f32
    float* Linv = Lsum + 128;              // 128 f32

    float l0[2];
    #pragma unroll
    for (int qt = 0; qt < 2; qt++)
        l0[qt] = lacc[qt] + __shfl_xor(lacc[qt], 32);

    if (kq == 1){
        #pragma unroll
        for (int qt = 0; qt < 2; qt++)
            Lsum[wq * 64 + qt * 32 + l32] = l0[qt];
        #pragma unroll
        for (int qt = 0; qt < 2; qt++)
            #pragma unroll
            for (int dt = 0; dt < 2; dt++)
                #pragma unroll
                for (int e = 0; e < 16; e++){
                    int qrow = wq * 64 + qt * 32 + (e & 3) + 8 * (e >> 2) + 4 * hi;
                    LO[qrow * 65 + dt * 32 + l32] = oacc[qt][dt][e];
                }
    }
    __syncthreads();
    if (kq == 0){
        #pragma unroll
        for (int qt = 0; qt < 2; qt++){
            float lt = l0[qt] + Lsum[wq * 64 + qt * 32 + l32];
            Linv[wq * 64 + qt * 32 + l32] = 1.0f / lt;
        }
        asm volatile("s_waitcnt lgkmcnt(0)" ::: "memory");
        #pragma unroll
        for (int qt = 0; qt < 2; qt++)
            #pragma unroll
            for (int dt = 0; dt < 2; dt++)
                #pragma unroll
                for (int e = 0; e < 16; e++){
                    int qrow = wq * 64 + qt * 32 + (e & 3) + 8 * (e >> 2) + 4 * hi;
                    float val = (oacc[qt][dt][e] + LO[qrow * 65 + dt * 32 + l32]) * Linv[qrow];
                    o[((size_t)(b * N_ + n0 + qrow)) * C_ + h * D_ + dt * 32 + l32] = f2b(val);
                }
    }
}

extern "C" void kernel_launch(void* const* d_in, const int* in_sizes, int n_in,
                              void* d_out, int out_size, void* d_ws, size_t ws_size,
                              hipStream_t stream) {
    const float* query = (const float*)d_in[0];
    const float* key   = (const float*)d_in[1];
    const int*   qpos  = (const int*)d_in[2];
    const int*   kpos  = (const int*)d_in[3];
    const float* Wq    = (const float*)d_in[4];
    const float* bq    = (const float*)d_in[5];
    const float* Wk    = (const float*)d_in[6];
    const float* Wv    = (const float*)d_in[7];
    const float* bv    = (const float*)d_in[8];
    const float* Wo    = (const float*)d_in[9];
    const float* bo    = (const float*)d_in[10];
    float* out = (float*)d_out;

    const size_t E4M = (size_t)4 * 1024 * 1024;
    const size_t E1M = (size_t)1024 * 1024;
    short* ws    = (short*)d_ws;
    short* qbf   = ws;                    // 4M (dead after proj -> reused as attn)
    short* kbf   = qbf   + E4M;           // 4M
    short* wqkvb = kbf   + E4M;           // 3M = [Wq;Wk;Wv]
    short* wob   = wqkvb + 3 * E1M;       // 1M
    short* qproj = wob   + E1M;           // 4M
    short* kproj = qproj + E4M;           // 4M
    short* vT    = kproj + E4M;           // 4M  -> total 24M shorts = 48 MB
    short* attn  = qbf;                   // alias

    // 1) fused converts (12M elements, contiguous dst)
    cvt_all<<<6144, 256, 0, stream>>>(query, key, Wq, Wk, Wv, Wo, ws);

    // 2) fused QKV projection; k-RoPE fused in epilogue; V stored transposed
    gemm_qkv<<<dim3(24, 32), 256, 0, stream>>>(qbf, kbf, wqkvb, bq, bv, kpos,
                                               qproj, kproj, vT);

    // 3) flash attention -> attn [B,N,C] bf16 (q-RoPE fused in prologue; XCD swizzle)
    flash_attn<<<512, 256, 0, stream>>>(qproj, kproj, vT, attn, qpos);

    // 4) output projection + bias + residual -> f32 out
    gemm_out<<<dim3(16, 32), 256, 0, stream>>>(attn, wob, bo, query, out);
}

// Round 14
// 203.415 us; speedup vs baseline: 1.0277x; 1.0277x over previous
//
#include <hip/hip_runtime.h>
#include <hip/hip_bf16.h>
#include <stdint.h>

#define B_ 2
#define N_ 2048
#define M_ 2048
#define C_ 1024
#define H_ 16
#define D_ 64

typedef __attribute__((ext_vector_type(8))) short s16x8;
typedef __attribute__((ext_vector_type(4))) short s16x4;
typedef __attribute__((ext_vector_type(4))) float f32x4;
typedef __attribute__((ext_vector_type(16))) float f32x16;

__device__ __attribute__((always_inline)) inline short f2b(float f){
    __hip_bfloat16 h = __float2bfloat16(f); short s; __builtin_memcpy(&s, &h, 2); return s;
}
__device__ __attribute__((always_inline)) inline float b2f(short s){
    __hip_bfloat16 h; __builtin_memcpy(&h, &s, 2); return __bfloat162float(h);
}

#define MFMA16(a,b,c) __builtin_amdgcn_mfma_f32_16x16x32_bf16(a,b,c,0,0,0)
#define MFMA32(a,b,c) __builtin_amdgcn_mfma_f32_32x32x16_bf16(a,b,c,0,0,0)

__device__ __attribute__((always_inline)) inline void gl_lds16(const void* g, void* l){
    __builtin_amdgcn_global_load_lds((__attribute__((address_space(1))) void*)g,
                                     (__attribute__((address_space(3))) void*)l, 16, 0, 0);
}
// pack two f32 -> one u32 of 2 bf16 (RNE), low short = first arg
__device__ __attribute__((always_inline)) inline unsigned cvtpk(float lo, float hi){
    unsigned r;
    asm("v_cvt_pk_bf16_f32 %0, %1, %2" : "=v"(r) : "v"(lo), "v"(hi));
    return r;
}
// a -> [a_lo | b_lo], b -> [a_hi | b_hi] across the lane<32 / lane>=32 split
__device__ __attribute__((always_inline)) inline void lane32swap(unsigned &a, unsigned &b){
    asm("v_permlane32_swap_b32 %0, %1" : "+v"(a), "+v"(b));
}

// ---------------- fused f32 -> bf16 convert: [query|key|Wq|Wk|Wv|Wo] -> ws[0..12M) ----
__global__ void cvt_all(const float* __restrict__ q, const float* __restrict__ k,
                        const float* __restrict__ wq, const float* __restrict__ wk,
                        const float* __restrict__ wv, const float* __restrict__ wo,
                        short* __restrict__ dst){
    long i = ((long)blockIdx.x * 256 + threadIdx.x) * 8;
    const float* src; long off;
    if      (i <  4194304L){ src = q;  off = i; }
    else if (i <  8388608L){ src = k;  off = i - 4194304L; }
    else if (i <  9437184L){ src = wq; off = i - 8388608L; }
    else if (i < 10485760L){ src = wk; off = i - 9437184L; }
    else if (i < 11534336L){ src = wv; off = i - 10485760L; }
    else                   { src = wo; off = i - 11534336L; }
    float4 a = *(const float4*)(src + off);
    float4 b = *(const float4*)(src + off + 4);
    s16x8 o;
    o[0]=f2b(a.x); o[1]=f2b(a.y); o[2]=f2b(a.z); o[3]=f2b(a.w);
    o[4]=f2b(b.x); o[5]=f2b(b.y); o[6]=f2b(b.z); o[7]=f2b(b.w);
    *(s16x8*)(dst + i) = o;
}

// ---------------- fused QKV projection GEMM ----------------
// A = qbf (n0<1024) or kbf; W = [Wq;Wk;Wv] (3072,1024) bf16 row-major.
// Epilogue: q -> +bq plain store; k -> fused RoPE (f32, in-register pair j/j+2) store;
// v -> +bv, LDS-transposed coalesced store to vT[b,h,d,m].
__global__ __launch_bounds__(256, 3) void gemm_qkv(
    const short* __restrict__ qbf, const short* __restrict__ kbf,
    const short* __restrict__ W,
    const float* __restrict__ bq, const float* __restrict__ bv,
    const int* __restrict__ kpos,
    short* __restrict__ qproj, short* __restrict__ kproj, short* __restrict__ vT)
{
    // sb: As = [0,4096), Bs = [4096,8192) during the k-loop;
    // whole 8704 shorts reused as Vt[64][136] in the V transpose epilogue.
    __shared__ short sb[8704];
    short* As = sb;
    short* Bs = sb + 4096;
    const int n0 = blockIdx.x * 128, m0 = blockIdx.y * 128;
    const int sel = n0 >> 10;                 // 0=q, 1=k, 2=v (block-uniform)
    const short* A = (sel == 0) ? qbf : kbf;
    const int tid = threadIdx.x, lane = tid & 63, wave = tid >> 6;
    const int quad = lane >> 4, l16 = lane & 15;
    const int wr = (wave >> 1) * 64, wc = (wave & 1) * 64;
    const int srow = lane >> 2, scol = (lane & 3) * 8;

    f32x4 acc[4][4] = {};

    const short* Ag = A + (size_t)(m0 + wave * 32 + srow) * C_ + scol;
    const short* Bg = W + (size_t)(n0 + wave * 32 + srow) * C_ + scol;
    short* lA0 = As + (wave * 32) * 32;
    short* lA1 = As + (wave * 32 + 16) * 32;
    short* lB0 = Bs + (wave * 32) * 32;
    short* lB1 = Bs + (wave * 32 + 16) * 32;

    for (int k0 = 0; k0 < C_; k0 += 32){
        __syncthreads();
        gl_lds16(Ag + k0, lA0);
        gl_lds16(Ag + k0 + 16 * (size_t)C_, lA1);
        gl_lds16(Bg + k0, lB0);
        gl_lds16(Bg + k0 + 16 * (size_t)C_, lB1);
        __syncthreads();
        s16x8 af[4], bfr[4];
        #pragma unroll
        for (int t = 0; t < 4; t++) af[t]  = *(const s16x8*)&As[(wr + t*16 + l16) * 32 + quad * 8];
        #pragma unroll
        for (int t = 0; t < 4; t++) bfr[t] = *(const s16x8*)&Bs[(wc + t*16 + l16) * 32 + quad * 8];
        #pragma unroll
        for (int i = 0; i < 4; i++)
            #pragma unroll
            for (int j = 0; j < 4; j++)
                acc[i][j] = MFMA16(af[i], bfr[j], acc[i][j]);
    }

    // C/D layout (m89-verified): row(m) = quad*4 + r, col(n) = l16
    if (sel == 0){
        #pragma unroll
        for (int j = 0; j < 4; j++){
            int c = n0 + wc + j * 16 + l16;
            float bb = bq[c];
            #pragma unroll
            for (int i = 0; i < 4; i++){
                int row = m0 + wr + i * 16 + quad * 4;
                #pragma unroll
                for (int r = 0; r < 4; r++)
                    qproj[(size_t)(row + r) * C_ + c] = f2b(acc[i][j][r] + bb);
            }
        }
    } else if (sel == 1){
        // K path: fused RoPE in f32. Pair (d, d+32) = (acc[i][j2], acc[i][j2+2]),
        // d = (wc + j2*16 + l16) & 63 in [0,32). row indexes kpos directly ([B*M]).
        #pragma unroll
        for (int j2 = 0; j2 < 2; j2++){
            int c1 = n0 - 1024 + wc + j2 * 16 + l16;     // col in [0,1024), d = c1&63 < 32
            int irot = c1 & 63;
            float invf = exp2f((float)irot * (-13.287712379549449f / 32.0f));
            #pragma unroll
            for (int i = 0; i < 4; i++){
                int row = m0 + wr + i * 16 + quad * 4;
                #pragma unroll
                for (int r = 0; r < 4; r++){
                    float pos = (float)kpos[row + r];
                    float ang = pos * invf;
                    float cs = __cosf(ang), sn = __sinf(ang);
                    float x1 = acc[i][j2][r], x2 = acc[i][j2 + 2][r];
                    kproj[(size_t)(row + r) * C_ + c1]      = f2b(x1 * cs - x2 * sn);
                    kproj[(size_t)(row + r) * C_ + c1 + 32] = f2b(x2 * cs + x1 * sn);
                }
            }
        }
    } else {
        // V: +bv, LDS transpose then coalesced store.
        short* Vt = sb;                       // [64 cols][136 stride] shorts
        const int bat = m0 >> 11;
        const int mbase = m0 & 2047;
        #pragma unroll
        for (int p = 0; p < 2; p++){
            __syncthreads();
            if ((wave & 1) == p){
                #pragma unroll
                for (int j = 0; j < 4; j++){
                    int c_local = j * 16 + l16;              // 0..63
                    float bb = bv[n0 - 2048 + p * 64 + c_local];
                    #pragma unroll
                    for (int i = 0; i < 4; i++){
                        int row = wr + i * 16 + quad * 4;    // 0..127
                        unsigned u0 = (unsigned)(unsigned short)f2b(acc[i][j][0] + bb) |
                                      ((unsigned)(unsigned short)f2b(acc[i][j][1] + bb) << 16);
                        unsigned u1 = (unsigned)(unsigned short)f2b(acc[i][j][2] + bb) |
                                      ((unsigned)(unsigned short)f2b(acc[i][j][3] + bb) << 16);
                        uint2 u; u.x = u0; u.y = u1;
                        *(uint2*)&Vt[c_local * 136 + row] = u;
                    }
                }
            }
            __syncthreads();
            #pragma unroll
            for (int it = 0; it < 4; it++){
                int qq = it * 256 + tid;
                int c_local = qq >> 4, mm = (qq & 15) * 8;
                int colg = n0 - 2048 + p * 64 + c_local;
                int hh = colg >> 6, dd = colg & 63;
                s16x8 v = *(const s16x8*)&Vt[c_local * 136 + mm];
                *(s16x8*)&vT[(((size_t)(bat * H_ + hh)) * D_ + dd) * M_ + mbase + mm] = v;
            }
        }
    }
}

// ---------------- final projection + bias + residual (f32 out) ----------------
__global__ __launch_bounds__(256, 4) void gemm_out(
    const short* __restrict__ A, const short* __restrict__ W,
    const float* __restrict__ bias, const float* __restrict__ resid,
    float* __restrict__ outf)
{
    __shared__ short As[128 * 32];
    __shared__ short Bs[64 * 32];
    const int n0 = blockIdx.x * 64, m0 = blockIdx.y * 128;
    const int tid = threadIdx.x, lane = tid & 63, wave = tid >> 6;
    const int quad = lane >> 4, l16 = lane & 15;
    const int srow = lane >> 2, scol = (lane & 3) * 8;

    f32x4 acc[2][4] = {};
    const short* Ag = A + (size_t)(m0 + wave * 32 + srow) * C_ + scol;
    const short* Bg = W + (size_t)(n0 + wave * 16 + srow) * C_ + scol;
    short* lA0 = As + (wave * 32) * 32;
    short* lA1 = As + (wave * 32 + 16) * 32;
    short* lB  = Bs + (wave * 16) * 32;

    for (int k0 = 0; k0 < C_; k0 += 32){
        __syncthreads();
        gl_lds16(Ag + k0, lA0);
        gl_lds16(Ag + k0 + 16 * (size_t)C_, lA1);
        gl_lds16(Bg + k0, lB);
        __syncthreads();
        s16x8 af[2], bfr[4];
        #pragma unroll
        for (int t = 0; t < 2; t++) af[t]  = *(const s16x8*)&As[(wave*32 + t*16 + l16) * 32 + quad * 8];
        #pragma unroll
        for (int t = 0; t < 4; t++) bfr[t] = *(const s16x8*)&Bs[(t*16 + l16) * 32 + quad * 8];
        #pragma unroll
        for (int i = 0; i < 2; i++)
            #pragma unroll
            for (int j = 0; j < 4; j++)
                acc[i][j] = MFMA16(af[i], bfr[j], acc[i][j]);
    }

    #pragma unroll
    for (int j = 0; j < 4; j++){
        int c = n0 + j * 16 + l16;
        float bb = bias[c];
        #pragma unroll
        for (int i = 0; i < 2; i++){
            int row = m0 + wave * 32 + i * 16 + quad * 4;
            #pragma unroll
            for (int r = 0; r < 4; r++){
                size_t idx = (size_t)(row + r) * C_ + c;
                outf[idx] = acc[i][j][r] + bb + resid[idx];
            }
        }
    }
}

// ---------------- Flash attention (128-q blocks, round-12 final: depth-2 pipe) ----
// Quad-buffered K/V staging with raw s_barrier (NO vmcnt drain at the barrier).
// Per step t: read buf[t&3] -> compute -> ds_write regs R (tile t+1, loaded during
// step t-1; counted vmcnt wait lands here with a full step of slack) -> issue loads
// tile t+2 -> lgkmcnt(0) -> s_barrier. Distance-2 buffers race-free under the
// one-barrier-per-step skew bound. P in-register via cvt_pk + permlane32_swap.
// T1 XCD-chunked grid swizzle: flat grid 512 = 8 XCDs x 64; XCD c serves (b,h) in
// [4c, 4c+4) -> 2MB K/V working set per 4MB L2 (measured FETCH 69.7 -> 12.4 MB).
__global__ __launch_bounds__(256, 2) void flash_attn(
    const short* __restrict__ q, const short* __restrict__ k,
    const short* __restrict__ vt, short* __restrict__ o,
    const int* __restrict__ qpos)
{
    // shorts: K[4] @0 (4*64*68=17408), V[4] @17408, Lsum/Linv @34816 (256 f32)
    __shared__ short smem[35328];
    // XCD-chunked bijective swizzle (512 % 8 == 0): xcd = bid&7 gets 64 contiguous ids
    const int bid = blockIdx.x;
    const int wgid = (bid & 7) * 64 + (bid >> 3);
    const int y = wgid >> 4;                 // (b,h) group: 4 per XCD
    const int n0 = (wgid & 15) * 128;        // q-block
    const int b = y >> 4, h = y & 15;
    const int tid = threadIdx.x, lane = tid & 63, wave = tid >> 6;
    const int hi = lane >> 5, l32 = lane & 31;
    const int wq = wave & 1, kq = wave >> 1;

    // Q fragments (B-operand: lane n = q row, k = d), with fused RoPE + scale*log2e
    s16x8 qf[2][4];
    const float fac = 0.18033688011112042f;   // 0.125 * log2(e)
    #pragma unroll
    for (int qt = 0; qt < 2; qt++){
        int qrow = n0 + wq * 64 + qt * 32 + l32;
        const short* qg = &q[((size_t)(b * N_ + qrow)) * C_ + h * D_];
        float pos = (float)qpos[b * N_ + qrow];
        s16x8 raw[4];
        #pragma unroll
        for (int c = 0; c < 4; c++) raw[c] = *(const s16x8*)&qg[c * 16 + hi * 8];
        #pragma unroll
        for (int c = 0; c < 2; c++){
            s16x8 olo, ohi8;
            #pragma unroll
            for (int j = 0; j < 8; j++){
                int irot = c * 16 + hi * 8 + j;
                float invf = exp2f((float)irot * (-13.287712379549449f / 32.0f));
                float ang = pos * invf;
                float cs = __cosf(ang), sn = __sinf(ang);
                float x1 = b2f(raw[c][j]), x2 = b2f(raw[c + 2][j]);
                olo[j]  = f2b((x1 * cs - x2 * sn) * fac);
                ohi8[j] = f2b((x2 * cs + x1 * sn) * fac);
            }
            qf[qt][c] = olo; qf[qt][c + 2] = ohi8;
        }
    }

    const short* kg = k  + (size_t)(b * M_) * C_ + h * D_;
    const short* vg = vt + ((size_t)(b * H_ + h)) * D_ * M_;
    const int srow0 = tid >> 3, sseg = (tid & 7) * 8;

    union V8 { s16x8 v; uint2 u[2]; };
    V8 kreg[2], vreg[2];

    // prologue: tile0 -> regs -> buf0; tile1 -> regs (held); barrier
    #pragma unroll
    for (int ii = 0; ii < 2; ii++){
        int row = srow0 + 32 * ii;
        kreg[ii].v = *(const s16x8*)&kg[(size_t)row * C_ + sseg];
        vreg[ii].v = *(const s16x8*)&vg[(size_t)row * M_ + sseg];
    }
    #pragma unroll
    for (int ii = 0; ii < 2; ii++){
        int row = srow0 + 32 * ii;
        short* kd = &smem[row * 68 + sseg];
        *(uint2*)kd = kreg[ii].u[0]; *(uint2*)(kd + 4) = kreg[ii].u[1];
        short* vd = &smem[17408 + row * 68 + sseg];
        *(uint2*)vd = vreg[ii].u[0]; *(uint2*)(vd + 4) = vreg[ii].u[1];
    }
    #pragma unroll
    for (int ii = 0; ii < 2; ii++){
        int row = srow0 + 32 * ii;
        kreg[ii].v = *(const s16x8*)&kg[(size_t)(64 + row) * C_ + sseg];
        vreg[ii].v = *(const s16x8*)&vg[(size_t)row * M_ + 64 + sseg];
    }
    asm volatile("s_waitcnt lgkmcnt(0)" ::: "memory");
    __builtin_amdgcn_s_barrier();

    f32x16 zero16 = {};
    f32x16 oacc[2][2] = {zero16, zero16, zero16, zero16};
    float lacc[2] = {0.f, 0.f};

    for (int st = 0; st < 32; st++){
        const int bi = st & 3;
        const short* Kp = &smem[bi * 4352];
        const short* Vp = &smem[17408 + bi * 4352];

        // issue all LDS reads early so they overlap the QK MFMAs
        s16x4 kf[4][2];
        #pragma unroll
        for (int c = 0; c < 4; c++){
            const short* a = &Kp[(kq * 32 + l32) * 68 + c * 16 + hi * 8];
            kf[c][0] = *(const s16x4*)a; kf[c][1] = *(const s16x4*)(a + 4);
        }
        s16x8 vf[2][2];
        #pragma unroll
        for (int dt = 0; dt < 2; dt++)
            #pragma unroll
            for (int c = 0; c < 2; c++){
                const short* a = &Vp[(dt * 32 + l32) * 68 + kq * 32 + c * 16 + hi * 8];
                vf[dt][c] = __builtin_shufflevector(*(const s16x4*)a, *(const s16x4*)(a + 4),
                                                    0,1,2,3,4,5,6,7);
            }

        // QK^T (S^T layout: lane = q-row, regs = k-rows) then softmax exp in-register.
        s16x8 pf[2][2];
        #pragma unroll
        for (int qt = 0; qt < 2; qt++){
            f32x16 sv = {};
            #pragma unroll
            for (int c = 0; c < 4; c++){
                s16x8 ka = __builtin_shufflevector(kf[c][0], kf[c][1], 0,1,2,3,4,5,6,7);
                sv = MFMA32(ka, qf[qt][c], sv);
            }
            float pe[16];
            #pragma unroll
            for (int e = 0; e < 16; e++) pe[e] = __builtin_amdgcn_exp2f(sv[e]);
            float ls = 0.f;
            #pragma unroll
            for (int e = 0; e < 16; e += 4) ls += (pe[e] + pe[e+1]) + (pe[e+2] + pe[e+3]);
            lacc[qt] += ls;
            #pragma unroll
            for (int c = 0; c < 2; c++){
                unsigned a1 = cvtpk(pe[8*c + 0], pe[8*c + 1]);
                unsigned a2 = cvtpk(pe[8*c + 2], pe[8*c + 3]);
                unsigned b1 = cvtpk(pe[8*c + 4], pe[8*c + 5]);
                unsigned b2 = cvtpk(pe[8*c + 6], pe[8*c + 7]);
                lane32swap(a1, b1);   // a1=[a1lo|b1lo] b1=[a1hi|b1hi]
                lane32swap(a2, b2);
                union { unsigned u[4]; s16x8 v; } pk;
                pk.u[0] = a1; pk.u[1] = a2; pk.u[2] = b1; pk.u[3] = b2;
                pf[qt][c] = pk.v;
            }
        }

        // PV: O[q][d] += P(64x32) . V(32x64), P fragments straight from registers
        #pragma unroll
        for (int qt = 0; qt < 2; qt++)
            #pragma unroll
            for (int dt = 0; dt < 2; dt++)
                #pragma unroll
                for (int c = 0; c < 2; c++)
                    oacc[qt][dt] = MFMA32(pf[qt][c], vf[dt][c], oacc[qt][dt]);

        // write tile st+1 (held in R since step st-1) into buf[(st+1)&3];
        // the counted vmcnt wait for those loads lands HERE with ~1 step of slack
        if (st < 31){
            int bn = (st + 1) & 3;
            #pragma unroll
            for (int ii = 0; ii < 2; ii++){
                int row = srow0 + 32 * ii;
                short* kd = &smem[bn * 4352 + row * 68 + sseg];
                *(uint2*)kd = kreg[ii].u[0]; *(uint2*)(kd + 4) = kreg[ii].u[1];
                short* vd = &smem[17408 + bn * 4352 + row * 68 + sseg];
                *(uint2*)vd = vreg[ii].u[0]; *(uint2*)(vd + 4) = vreg[ii].u[1];
            }
        }
        // issue loads for tile st+2 -> R (stay in flight across the next step)
        if (st < 30){
            #pragma unroll
            for (int ii = 0; ii < 2; ii++){
                int row = srow0 + 32 * ii;
                kreg[ii].v = *(const s16x8*)&kg[((size_t)((st + 2) * 64 + row)) * C_ + sseg];
                vreg[ii].v = *(const s16x8*)&vg[(size_t)row * M_ + (st + 2) * 64 + sseg];
            }
        }
        // drain LDS ops (my ds_writes visible), then raw barrier (vmcnt NOT drained)
        asm volatile("s_waitcnt lgkmcnt(0)" ::: "memory");
        __builtin_amdgcn_s_barrier();
    }

    __syncthreads();   // full drain before overlaying K/V buffers

    float* LO   = (float*)smem;            // [128][65] f32 (overlays K bufs, 33.3KB)
    float* Lsum = (float*)&smem[34816];    // 128 f32
    float* Linv = Lsum + 128;              // 128 f32

    float l0[2];
    #pragma unroll
    for (int qt = 0; qt < 2; qt++)
        l0[qt] = lacc[qt] + __shfl_xor(lacc[qt], 32);

    if (kq == 1){
        #pragma unroll
        for (int qt = 0; qt < 2; qt++)
            Lsum[wq * 64 + qt * 32 + l32] = l0[qt];
        #pragma unroll
        for (int qt = 0; qt < 2; qt++)
            #pragma unroll
            for (int dt = 0; dt < 2; dt++)
                #pragma unroll
                for (int e = 0; e < 16; e++){
                    int qrow = wq * 64 + qt * 32 + (e & 3) + 8 * (e >> 2) + 4 * hi;
                    LO[qrow * 65 + dt * 32 + l32] = oacc[qt][dt][e];
                }
    }
    __syncthreads();
    if (kq == 0){
        #pragma unroll
        for (int qt = 0; qt < 2; qt++){
            float lt = l0[qt] + Lsum[wq * 64 + qt * 32 + l32];
            Linv[wq * 64 + qt * 32 + l32] = 1.0f / lt;
        }
        asm volatile("s_waitcnt lgkmcnt(0)" ::: "memory");
        #pragma unroll
        for (int qt = 0; qt < 2; qt++)
            #pragma unroll
            for (int dt = 0; dt < 2; dt++)
                #pragma unroll
                for (int e = 0; e < 16; e++){
                    int qrow = wq * 64 + qt * 32 + (e & 3) + 8 * (e >> 2) + 4 * hi;
                    float val = (oacc[qt][dt][e] + LO[qrow * 65 + dt * 32 + l32]) * Linv[qrow];
                    o[((size_t)(b * N_ + n0 + qrow)) * C_ + h * D_ + dt * 32 + l32] = f2b(val);
                }
    }
}

extern "C" void kernel_launch(void* const* d_in, const int* in_sizes, int n_in,
                              void* d_out, int out_size, void* d_ws, size_t ws_size,
                              hipStream_t stream) {
    const float* query = (const float*)d_in[0];
    const float* key   = (const float*)d_in[1];
    const int*   qpos  = (const int*)d_in[2];
    const int*   kpos  = (const int*)d_in[3];
    const float* Wq    = (const float*)d_in[4];
    const float* bq    = (const float*)d_in[5];
    const float* Wk    = (const float*)d_in[6];
    const float* Wv    = (const float*)d_in[7];
    const float* bv    = (const float*)d_in[8];
    const float* Wo    = (const float*)d_in[9];
    const float* bo    = (const float*)d_in[10];
    float* out = (float*)d_out;

    const size_t E4M = (size_t)4 * 1024 * 1024;
    const size_t E1M = (size_t)1024 * 1024;
    short* ws    = (short*)d_ws;
    short* qbf   = ws;                    // 4M (dead after proj -> reused as attn)
    short* kbf   = qbf   + E4M;           // 4M
    short* wqkvb = kbf   + E4M;           // 3M = [Wq;Wk;Wv]
    short* wob   = wqkvb + 3 * E1M;       // 1M
    short* qproj = wob   + E1M;           // 4M
    short* kproj = qproj + E4M;           // 4M
    short* vT    = kproj + E4M;           // 4M  -> total 24M shorts = 48 MB
    short* attn  = qbf;                   // alias

    // 1) fused converts (12M elements, contiguous dst)
    cvt_all<<<6144, 256, 0, stream>>>(query, key, Wq, Wk, Wv, Wo, ws);

    // 2) fused QKV projection; k-RoPE fused in epilogue; V stored transposed
    gemm_qkv<<<dim3(24, 32), 256, 0, stream>>>(qbf, kbf, wqkvb, bq, bv, kpos,
                                               qproj, kproj, vT);

    // 3) flash attention -> attn [B,N,C] bf16 (q-RoPE fused in prologue; XCD swizzle)
    flash_attn<<<512, 256, 0, stream>>>(qproj, kproj, vT, attn, qpos);

    // 4) output projection + bias + residual -> f32 out
    gemm_out<<<dim3(16, 32), 256, 0, stream>>>(attn, wob, bo, query, out);
}